// Round 7
// baseline (497.978 us; speedup 1.0000x reference)
//
#include <hip/hip_runtime.h>
#include <hip/hip_bf16.h>
#include <hip/hip_cooperative_groups.h>

namespace cg = cooperative_groups;

#define BATCH 16
#define T 256
#define DHW 5760  // 3*30*64
#define HPAD 264  // padded bf16 row stride for h in LDS

typedef __bf16 bf16x8 __attribute__((ext_vector_type(8)));
typedef float f32x4 __attribute__((ext_vector_type(4)));

// ---------- gate nonlinearities: odd Taylor, |arg| <~ 0.5 ----------
__device__ __forceinline__ float tanh7(float x) {
    float t = x * x;
    float p = fmaf(t, fmaf(t, fmaf(t, -17.0f / 315.0f, 2.0f / 15.0f), -1.0f / 3.0f), 1.0f);
    return x * p;
}
__device__ __forceinline__ float sigm(float x) {
    float u = 0.5f * x;
    float t = u * u;
    float p = fmaf(t, fmaf(t, 2.0f / 15.0f, -1.0f / 3.0f), 1.0f);
    return fmaf(0.5f * u, p, 0.5f);
}

__global__ __launch_bounds__(1024, 1) void mega_kernel(
    const float* __restrict__ x,       // [16][256][5760]
    const float* __restrict__ conv_w,  // [256][256][3]
    const float* __restrict__ conv_b,  // [256]
    const float* __restrict__ w_ih,    // [768][256]
    const float* __restrict__ b_ih,    // [768]
    const float* __restrict__ w_hh,    // [768][256]
    const float* __restrict__ b_hh,    // [768]
    float* __restrict__ out,           // [16][256][256]
    float* __restrict__ g,             // ws: [16][256]
    float* __restrict__ maskb,         // ws: [16][256]
    float* __restrict__ gib,           // ws: [16][768]
    int* __restrict__ meta)            // ws: [1] = S
{
    cg::grid_group grid = cg::this_grid();
    const int blk = blockIdx.x;
    const int tid = threadIdx.x;
    const int w = tid >> 6, lane = tid & 63;
    const int l15 = lane & 15, quad = lane >> 4;

    __shared__ __align__(16) __bf16 hb0[BATCH * HPAD];  // 8448 B
    __shared__ __align__(16) __bf16 hb1[BATCH * HPAD];  // 8448 B
    __shared__ __align__(16) float Xr[4096];            // per-lane r C-init
    __shared__ __align__(16) float Xz[4096];            // per-lane z C-init
    __shared__ float part[16][4];
    __shared__ int chg[64];

    // ---------------- phase 0: block 0 prefetches GRU weights; others pool ----
    bf16x8 bw[3][8];
    if (blk == 0) {
        const int col = 16 * w + l15;
        #pragma unroll
        for (int gg = 0; gg < 3; ++gg) {
            const float* wr = w_hh + (size_t)(gg * 256 + col) * T + quad * 8;
            #pragma unroll
            for (int kc = 0; kc < 8; ++kc) {
                const float4* p = (const float4*)(wr + kc * 32);
                float4 v0 = p[0], v1 = p[1];
                bf16x8 v;
                v[0] = (__bf16)v0.x; v[1] = (__bf16)v0.y; v[2] = (__bf16)v0.z; v[3] = (__bf16)v0.w;
                v[4] = (__bf16)v1.x; v[5] = (__bf16)v1.y; v[6] = (__bf16)v1.z; v[7] = (__bf16)v1.w;
                bw[gg][kc] = v;
            }
        }
        for (int idx = tid; idx < BATCH * HPAD; idx += 1024) {
            hb0[idx] = (__bf16)0.0f;
            hb1[idx] = (__bf16)0.0f;
        }
        if (tid < 64) chg[tid] = 0;
    } else {
        // pool: one row per wave; blocks 1..255 x 16 waves cover 4080, wrap for last 16
        const int gw = (blk - 1) * 16 + w;
        for (int r = gw; r < 4096; r += 4080) {
            const float4* xr = (const float4*)(x + (size_t)r * DHW);
            float s = 0.0f;
            for (int i = lane; i < DHW / 4; i += 64) {
                float4 v = xr[i];
                s += (v.x + v.y) + (v.z + v.w);
            }
            #pragma unroll
            for (int off = 32; off; off >>= 1) s += __shfl_down(s, off, 64);
            if (lane == 0) g[r] = s * (1.0f / (float)DHW);
        }
    }
    grid.sync();

    // ---------------- phase 1: mask[:, o] on blocks 1..255 (block 1 takes o=0,255)
    if (blk >= 1) {
        for (int o = blk - 1; o < 256; o += 255) {
            const int rep = tid >> 8;    // 0..3 -> batches 4rep..4rep+3
            const int ol = tid & 255;
            const float wt = conv_w[o * 768 + 3 * ol + 1];  // middle tap
            #pragma unroll
            for (int bb = 0; bb < 4; ++bb) {
                const int b = rep * 4 + bb;
                float v = wt * g[b * 256 + ol];
                #pragma unroll
                for (int off = 32; off; off >>= 1) v += __shfl_down(v, off, 64);
                if (lane == 0) part[b][(tid >> 6) & 3] = v;
            }
            __syncthreads();
            if (tid < 16)
                maskb[tid * 256 + o] = part[tid][0] + part[tid][1] + part[tid][2] + part[tid][3] + conv_b[o];
            __syncthreads();
        }
    }
    grid.sync();

    // ---------------- phase 2: gi[:, j] on blocks 1..255 (3-4 j's each) --------
    if (blk >= 1) {
        for (int j = blk - 1; j < 768; j += 255) {
            const int rep = tid >> 8;
            const int ol = tid & 255;
            const float wt = w_ih[j * 256 + ol];
            #pragma unroll
            for (int bb = 0; bb < 4; ++bb) {
                const int b = rep * 4 + bb;
                float v = wt * maskb[b * 256 + ol];
                #pragma unroll
                for (int off = 32; off; off >>= 1) v += __shfl_down(v, off, 64);
                if (lane == 0) part[b][(tid >> 6) & 3] = v;
            }
            __syncthreads();
            if (tid < 16)
                gib[tid * 768 + j] = part[tid][0] + part[tid][1] + part[tid][2] + part[tid][3] + b_ih[j];
            __syncthreads();
        }
    }
    grid.sync();

    // ---------------- phase 3: GRU recurrence on block 0 only ------------------
    if (blk == 0) {
        const int col = 16 * w + l15;
        const int b0 = quad * 4;
        {
            f32x4 vr, vz;
            #pragma unroll
            for (int i = 0; i < 4; ++i) {
                const float* gb = gib + (size_t)(b0 + i) * 768;
                vr[i] = gb[col] + b_hh[col];
                vz[i] = gb[256 + col] + b_hh[256 + col];
            }
            *(f32x4*)&Xr[tid * 4] = vr;   // per-lane slots, no cross-thread reads
            *(f32x4*)&Xz[tid * 4] = vz;
        }
        const float bn = b_hh[512 + col];
        f32x4 gn;
        #pragma unroll
        for (int i = 0; i < 4; ++i) gn[i] = gib[(size_t)(b0 + i) * 768 + 512 + col];

        const int aoff = l15 * HPAD + quad * 8;  // A-frag: m=l15(batch), k=quad*8+j
        const int hoff = b0 * HPAD + col;
        unsigned ooff = (unsigned)b0 * 65536u + (unsigned)col;
        f32x4 hold = {0.0f, 0.0f, 0.0f, 0.0f};
        __syncthreads();  // hb zero-init + chg visible to all block-0 waves

        // NOTE: __syncthreads() (NOT a raw s_waitcnt/s_barrier pair) is required
        // here: the raw intrinsics are IntrNoMem in LLVM, so the compiler may
        // reorder the ds_write(h)/ds_read(h) across them — R5/R6's 3e-3 absmax.
        auto gru_step = [&](const __bf16* __restrict__ curb, __bf16* __restrict__ nxtb,
                            bool check, int chunk) {
            f32x4 aR = *(const f32x4*)&Xr[tid * 4];
            f32x4 aZ = *(const f32x4*)&Xz[tid * 4];
            f32x4 aN  = {0, 0, 0, 0};
            f32x4 aR1 = {0, 0, 0, 0}, aZ1 = {0, 0, 0, 0}, aN1 = {0, 0, 0, 0};
            const __bf16* ar = curb + aoff;
            #pragma unroll
            for (int kc = 0; kc < 4; ++kc) {  // two 4-deep chains per gate
                bf16x8 a0 = *(const bf16x8*)(ar + kc * 32);
                bf16x8 a1 = *(const bf16x8*)(ar + (kc + 4) * 32);
                aR  = __builtin_amdgcn_mfma_f32_16x16x32_bf16(a0, bw[0][kc], aR, 0, 0, 0);
                aR1 = __builtin_amdgcn_mfma_f32_16x16x32_bf16(a1, bw[0][kc + 4], aR1, 0, 0, 0);
                aZ  = __builtin_amdgcn_mfma_f32_16x16x32_bf16(a0, bw[1][kc], aZ, 0, 0, 0);
                aZ1 = __builtin_amdgcn_mfma_f32_16x16x32_bf16(a1, bw[1][kc + 4], aZ1, 0, 0, 0);
                aN  = __builtin_amdgcn_mfma_f32_16x16x32_bf16(a0, bw[2][kc], aN, 0, 0, 0);
                aN1 = __builtin_amdgcn_mfma_f32_16x16x32_bf16(a1, bw[2][kc + 4], aN1, 0, 0, 0);
            }
            bool moving = false;
            #pragma unroll
            for (int i = 0; i < 4; ++i) {
                float r = sigm(aR[i] + aR1[i]);
                float z = sigm(aZ[i] + aZ1[i]);
                float n = tanh7(fmaf(r, aN[i] + aN1[i] + bn, gn[i]));
                float h = fmaf(z, hold[i] - n, n);
                if (check) moving |= (fabsf(h - hold[i]) > 1e-4f);  // proven eps (R4)
                hold[i] = h;
                nxtb[hoff + i * HPAD] = (__bf16)h;
                out[ooff + (unsigned)i * 65536u] = h;  // fire-and-forget
            }
            ooff += 256u;
            if (check) {
                if (__any(moving) && lane == 0) chg[chunk] = 1;
            }
            __syncthreads();
        };

        int S = T - 1;
        for (int chunk = 0; chunk < 64; ++chunk) {
            gru_step(hb0, hb1, false, 0);
            gru_step(hb1, hb0, false, 0);
            gru_step(hb0, hb1, false, 0);
            gru_step(hb1, hb0, true, chunk);
            if (chg[chunk] == 0) { S = chunk * 4 + 3; break; }
        }
        if (tid == 0) meta[0] = S;
        __threadfence();  // drain out-stores + make meta visible device-wide
    }
    grid.sync();

    // ---------------- phase 4: replicate row S into rows S+1..255 --------------
    {
        const int S = meta[0];
        const int c = tid & 255, bb = tid >> 8;
        for (int r = S + 1 + blk; r < 256; r += 256) {
            #pragma unroll
            for (int b = bb; b < 16; b += 4)
                out[b * 65536 + r * 256 + c] = out[b * 65536 + S * 256 + c];
        }
    }
}

extern "C" void kernel_launch(void* const* d_in, const int* in_sizes, int n_in,
                              void* d_out, int out_size, void* d_ws, size_t ws_size,
                              hipStream_t stream) {
    const float* x      = (const float*)d_in[0];
    const float* conv_w = (const float*)d_in[1];
    const float* conv_b = (const float*)d_in[2];
    const float* w_ih   = (const float*)d_in[3];
    const float* w_hh   = (const float*)d_in[4];
    const float* b_ih   = (const float*)d_in[5];
    const float* b_hh   = (const float*)d_in[6];
    float* out = (float*)d_out;

    float* ws    = (float*)d_ws;
    float* g     = ws;                 // 4096
    float* maskb = ws + 4096;          // 4096
    float* gib   = ws + 8192;          // 12288
    int*   meta  = (int*)(ws + 20480); // 1

    void* args[] = {&x, &conv_w, &conv_b, &w_ih, &b_ih, &w_hh, &b_hh,
                    &out, &g, &maskb, &gib, &meta};
    hipLaunchCooperativeKernel((const void*)mega_kernel, dim3(256), dim3(1024),
                               args, 0, stream);
}

// Round 9
// 302.707 us; speedup vs baseline: 1.6451x; 1.6451x over previous
//
#include <hip/hip_runtime.h>
#include <hip/hip_bf16.h>

#define BATCH 16
#define T 256
#define DHW 5760  // 3*30*64
#define HPAD 264  // padded bf16 row stride for h in LDS

typedef __bf16 bf16x8 __attribute__((ext_vector_type(8)));
typedef __bf16 bf16x4 __attribute__((ext_vector_type(4)));
typedef float f32x4 __attribute__((ext_vector_type(4)));

// ---------- gate nonlinearities: odd Taylor, |arg| <~ 0.5 ----------
__device__ __forceinline__ float tanh7(float x) {
    float t = x * x;
    float p = fmaf(t, fmaf(t, fmaf(t, -17.0f / 315.0f, 2.0f / 15.0f), -1.0f / 3.0f), 1.0f);
    return x * p;
}
__device__ __forceinline__ float sigm(float x) {
    float u = 0.5f * x;
    float t = u * u;
    float p = fmaf(t, fmaf(t, 2.0f / 15.0f, -1.0f / 3.0f), 1.0f);
    return fmaf(0.5f * u, p, 0.5f);
}

// ---------- kernel W: w_hh f32 -> bf16, row-major [768][256] ----------
__global__ void wcvt_kernel(const float* __restrict__ w_hh, __bf16* __restrict__ wbf) {
    const int idx = blockIdx.x * 256 + threadIdx.x;
    const float4 v = ((const float4*)w_hh)[idx];
    bf16x4 o;
    o[0] = (__bf16)v.x; o[1] = (__bf16)v.y; o[2] = (__bf16)v.z; o[3] = (__bf16)v.w;
    *(bf16x4*)(wbf + (size_t)idx * 4) = o;
}

// ---------- kernel A: global average pool ----------
__global__ void pool_kernel(const float* __restrict__ x, float* __restrict__ g) {
    const int row = blockIdx.x;
    const float4* xr = (const float4*)(x + (size_t)row * DHW);
    float s = 0.0f;
    for (int i = threadIdx.x; i < DHW / 4; i += 256) {
        float4 v = xr[i];
        s += (v.x + v.y) + (v.z + v.w);
    }
    #pragma unroll
    for (int off = 32; off > 0; off >>= 1) s += __shfl_down(s, off, 64);
    __shared__ float red[4];
    const int lane = threadIdx.x & 63, wv = threadIdx.x >> 6;
    if (lane == 0) red[wv] = s;
    __syncthreads();
    if (threadIdx.x == 0) {
        float t = (red[0] + red[1]) + (red[2] + red[3]);
        g[row] = t * (1.0f / (float)DHW);
    }
}

// ---------- kernel B1 ----------
__global__ void mask_kernel(const float* __restrict__ g, const float* __restrict__ conv_w,
                            const float* __restrict__ conv_b, float* __restrict__ mask) {
    const int o = blockIdx.x, i = threadIdx.x;
    const int lane = i & 63, wv = i >> 6;
    const float wt = conv_w[o * 768 + 3 * i + 1];
    __shared__ float part[16][4];
    #pragma unroll 4
    for (int b = 0; b < 16; ++b) {
        float v = wt * g[b * 256 + i];
        #pragma unroll
        for (int off = 32; off > 0; off >>= 1) v += __shfl_down(v, off, 64);
        if (lane == 0) part[b][wv] = v;
    }
    __syncthreads();
    if (i < 16)
        mask[i * 256 + o] = part[i][0] + part[i][1] + part[i][2] + part[i][3] + conv_b[o];
}

// ---------- kernel B2 ----------
__global__ void gi_kernel(const float* __restrict__ mask, const float* __restrict__ w_ih,
                          const float* __restrict__ b_ih, float* __restrict__ gi) {
    const int j = blockIdx.x, o = threadIdx.x;
    const int lane = o & 63, wv = o >> 6;
    const float wt = w_ih[j * 256 + o];
    __shared__ float part[16][4];
    #pragma unroll 4
    for (int b = 0; b < 16; ++b) {
        float v = wt * mask[b * 256 + o];
        #pragma unroll
        for (int off = 32; off > 0; off >>= 1) v += __shfl_down(v, off, 64);
        if (lane == 0) part[b][wv] = v;
    }
    __syncthreads();
    if (o < 16) gi[o * 768 + j] = part[o][0] + part[o][1] + part[o][2] + part[o][3] + b_ih[j];
}

// ---------- kernel C: GRU, one CU, 8 waves, 6 tiles/wave, weights PINNED in regs ----------
// wave w owns h-columns [32w, 32w+32): groups g0=[32w,32w+16), g1=[+16,+32); gates r,z,n each
__global__ __launch_bounds__(512, 1) void gru_kernel(
    const float* __restrict__ gi,    // [16][768]
    const __bf16* __restrict__ wbf,  // [768][256] bf16
    const float* __restrict__ b_hh,  // [768]
    float* __restrict__ out,         // [16][256][256]
    int* __restrict__ meta)          // [0] = S
{
    __shared__ __align__(16) __bf16 hb0[BATCH * HPAD];
    __shared__ __align__(16) __bf16 hb1[BATCH * HPAD];
    __shared__ __align__(16) float Xr0[2048], Xr1[2048];  // r C-init per lane (dense b128)
    __shared__ __align__(16) float Xz0[2048], Xz1[2048];
    __shared__ __align__(16) float Xn0[2048], Xn1[2048];  // gi_n per lane
    __shared__ int chg[64];

    const int tid = threadIdx.x;
    const int w = tid >> 6;
    const int lane = tid & 63;
    const int l15 = lane & 15;
    const int quad = lane >> 4;
    const int col0 = 32 * w + l15;      // group-0 column
    const int col1 = col0 + 16;         // group-1 column
    const int b0 = quad * 4;            // batch base

    // ---- weights: 6 B-frag tiles (r0,r1,z0,z1,n0,n1), 192 VGPRs ----
    bf16x8 bw[6][8];
    #pragma unroll
    for (int t = 0; t < 6; ++t) {
        const int gate = t >> 1, grp = t & 1;
        const __bf16* wr = wbf + (size_t)(gate * 256 + 32 * w + 16 * grp + l15) * 256 + quad * 8;
        #pragma unroll
        for (int kc = 0; kc < 8; ++kc)
            bw[t][kc] = *(const bf16x8*)(wr + kc * 32);
    }
    // Pin: values become opaque -> compiler cannot re-load from wbf each step
    // (R1-R8 streamed 384 KB/step from L2; VGPR_Count 64 was the tell).
    #pragma unroll
    for (int t = 0; t < 6; ++t)
        #pragma unroll
        for (int kc = 0; kc < 8; ++kc)
            asm volatile("" : "+v"(bw[t][kc]));

    // ---- per-lane C-init / gi_n into dense LDS slots; biases in regs ----
    {
        f32x4 r0, r1, z0, z1, n0, n1;
        #pragma unroll
        for (int i = 0; i < 4; ++i) {
            const float* gb = gi + (size_t)(b0 + i) * 768;
            r0[i] = gb[col0] + b_hh[col0];
            r1[i] = gb[col1] + b_hh[col1];
            z0[i] = gb[256 + col0] + b_hh[256 + col0];
            z1[i] = gb[256 + col1] + b_hh[256 + col1];
            n0[i] = gb[512 + col0];
            n1[i] = gb[512 + col1];
        }
        *(f32x4*)&Xr0[tid * 4] = r0; *(f32x4*)&Xr1[tid * 4] = r1;
        *(f32x4*)&Xz0[tid * 4] = z0; *(f32x4*)&Xz1[tid * 4] = z1;
        *(f32x4*)&Xn0[tid * 4] = n0; *(f32x4*)&Xn1[tid * 4] = n1;
    }
    const float bn0 = b_hh[512 + col0];
    const float bn1 = b_hh[512 + col1];

    for (int idx = tid; idx < BATCH * HPAD; idx += 512) {
        hb0[idx] = (__bf16)0.0f;
        hb1[idx] = (__bf16)0.0f;
    }
    if (tid < 64) chg[tid] = 0;

    const int aoff = l15 * HPAD + quad * 8;  // A-frag: m=l15(batch), k=quad*8+j
    const int hoff0 = b0 * HPAD + col0;
    const int hoff1 = b0 * HPAD + col1;
    unsigned ooff0 = (unsigned)b0 * 65536u + (unsigned)col0;
    unsigned ooff1 = (unsigned)b0 * 65536u + (unsigned)col1;

    f32x4 h0 = {0, 0, 0, 0}, h1 = {0, 0, 0, 0};  // current h (also pending out row)

    __syncthreads();

    // one step: h(curb) -> h(nxtb); new h kept in h0/h1 (stored by next flush)
    auto gstep = [&](const __bf16* __restrict__ curb, __bf16* __restrict__ nxtb,
                     bool check, int chunk) {
        f32x4 aR0 = *(const f32x4*)&Xr0[tid * 4];
        f32x4 aR1 = *(const f32x4*)&Xr1[tid * 4];
        f32x4 aZ0 = *(const f32x4*)&Xz0[tid * 4];
        f32x4 aZ1 = *(const f32x4*)&Xz1[tid * 4];
        f32x4 aN0 = {0, 0, 0, 0}, aN1 = {0, 0, 0, 0};
        const __bf16* ar = curb + aoff;
        #pragma unroll
        for (int kc = 0; kc < 8; ++kc) {  // A shared by all 6 tiles
            bf16x8 a = *(const bf16x8*)(ar + kc * 32);
            aR0 = __builtin_amdgcn_mfma_f32_16x16x32_bf16(a, bw[0][kc], aR0, 0, 0, 0);
            aR1 = __builtin_amdgcn_mfma_f32_16x16x32_bf16(a, bw[1][kc], aR1, 0, 0, 0);
            aZ0 = __builtin_amdgcn_mfma_f32_16x16x32_bf16(a, bw[2][kc], aZ0, 0, 0, 0);
            aZ1 = __builtin_amdgcn_mfma_f32_16x16x32_bf16(a, bw[3][kc], aZ1, 0, 0, 0);
            aN0 = __builtin_amdgcn_mfma_f32_16x16x32_bf16(a, bw[4][kc], aN0, 0, 0, 0);
            aN1 = __builtin_amdgcn_mfma_f32_16x16x32_bf16(a, bw[5][kc], aN1, 0, 0, 0);
        }
        const f32x4 gn0 = *(const f32x4*)&Xn0[tid * 4];
        const f32x4 gn1 = *(const f32x4*)&Xn1[tid * 4];
        bool mv = false;
        #pragma unroll
        for (int i = 0; i < 4; ++i) {
            float r = sigm(aR0[i]);
            float z = sigm(aZ0[i]);
            float n = tanh7(fmaf(r, aN0[i] + bn0, gn0[i]));
            float h = fmaf(z, h0[i] - n, n);
            if (check) mv |= (fabsf(h - h0[i]) > 1e-4f);
            h0[i] = h;
            nxtb[hoff0 + i * HPAD] = (__bf16)h;
        }
        #pragma unroll
        for (int i = 0; i < 4; ++i) {
            float r = sigm(aR1[i]);
            float z = sigm(aZ1[i]);
            float n = tanh7(fmaf(r, aN1[i] + bn1, gn1[i]));
            float h = fmaf(z, h1[i] - n, n);
            if (check) mv |= (fabsf(h - h1[i]) > 1e-4f);
            h1[i] = h;
            nxtb[hoff1 + i * HPAD] = (__bf16)h;
        }
        if (check) {
            if (__any(mv) && lane == 0) chg[chunk] = 1;
        }
        __syncthreads();
    };

    // store previous step's h to out; issued right AFTER a barrier so the stores
    // drain during the following step's compute (next vmcnt(0) wait finds them done)
    auto flush = [&]() {
        #pragma unroll
        for (int i = 0; i < 4; ++i) {
            out[ooff0 + (unsigned)i * 65536u] = h0[i];
            out[ooff1 + (unsigned)i * 65536u] = h1[i];
        }
        ooff0 += 256u; ooff1 += 256u;
    };

    gstep(hb0, hb1, false, 0);  // s=0 (no previous row to flush)
    int S = 255;
    for (int c = 0; c < 63; ++c) {  // steps 4c+1 .. 4c+4
        flush(); gstep(hb1, hb0, false, 0);
        flush(); gstep(hb0, hb1, false, 0);
        flush(); gstep(hb1, hb0, false, 0);
        flush(); gstep(hb0, hb1, true, c);
        if (chg[c] == 0) { S = 4 * c + 4; break; }
    }
    if (S == 255) {  // no convergence: finish steps 253..255
        flush(); gstep(hb1, hb0, false, 0);
        flush(); gstep(hb0, hb1, false, 0);
        flush(); gstep(hb1, hb0, false, 0);
    }
    flush();  // store row S
    if (tid == 0) meta[0] = S;
}

// ---------- kernel D: replicate row S into rows S+1..255 ----------
__global__ void fill_kernel(const int* __restrict__ meta, float* __restrict__ out) {
    const int S = meta[0];
    const int r = S + 1 + blockIdx.x;
    if (r > 255) return;
    const int c = threadIdx.x;
    #pragma unroll 4
    for (int b = 0; b < 16; ++b)
        out[b * 65536 + r * 256 + c] = out[b * 65536 + S * 256 + c];
}

extern "C" void kernel_launch(void* const* d_in, const int* in_sizes, int n_in,
                              void* d_out, int out_size, void* d_ws, size_t ws_size,
                              hipStream_t stream) {
    const float* x      = (const float*)d_in[0];
    const float* conv_w = (const float*)d_in[1];
    const float* conv_b = (const float*)d_in[2];
    const float* w_ih   = (const float*)d_in[3];
    const float* w_hh   = (const float*)d_in[4];
    const float* b_ih   = (const float*)d_in[5];
    const float* b_hh   = (const float*)d_in[6];
    float* out = (float*)d_out;

    float* ws    = (float*)d_ws;
    float* g     = ws;                       // 4096 floats
    float* maskb = ws + 4096;                // 4096
    float* gib   = ws + 8192;                // 12288
    int*   meta  = (int*)(ws + 20480);       // 1
    __bf16* wbf  = (__bf16*)(ws + 20608);    // 196608 bf16 (384 KB), 16B-aligned

    wcvt_kernel<<<192, 256, 0, stream>>>(w_hh, wbf);
    pool_kernel<<<BATCH * T, 256, 0, stream>>>(x, g);
    mask_kernel<<<T, 256, 0, stream>>>(g, conv_w, conv_b, maskb);
    gi_kernel<<<3 * T, 256, 0, stream>>>(maskb, w_ih, b_ih, gib);
    gru_kernel<<<1, 512, 0, stream>>>(gib, wbf, b_hh, out, meta);
    fill_kernel<<<T - 1, 256, 0, stream>>>(meta, out);
}